// Round 3
// baseline (1795.197 us; speedup 1.0000x reference)
//
#include <hip/hip_runtime.h>
#include <hip/hip_bf16.h>

#define BB 8
#define LL 1024
#define TT 10
#define TILE 64
#define NTILE 16
#define NOFF 120                 // off-diag pairs per batch (I<J)
#define NBLK 1024                // 960 offdiag + 64 merged-diag = exactly 4/CU
#define S_CONST 2.1972245773362196f

typedef __hip_bfloat16 bf16;

static __device__ __forceinline__ float sigm(float v) {
    return 1.0f / (1.0f + __expf(-v));
}
static __device__ __forceinline__ unsigned short f2bf(float v) {
    bf16 h = __float2bfloat16(v);   // RNE, same rounding as round-1 (passing)
    unsigned short b; __builtin_memcpy(&b, &h, 2); return b;
}
static __device__ __forceinline__ float lo2f(unsigned int v) { return __uint_as_float(v << 16); }
static __device__ __forceinline__ float hi2f(unsigned int v) { return __uint_as_float(v & 0xffff0000u); }
static __device__ __forceinline__ unsigned int pk2(float uu, float ah) {
    return (unsigned int)f2bf(uu) | ((unsigned int)f2bf(ah) << 16);
}

// manual grid barrier: per-slot arrival counter (zeroed by host memset each launch).
// Co-residency of all NBLK blocks is guaranteed by resource math:
// LDS 37536B (<40KiB) and VGPR<=128 (launch_bounds) -> exactly 4 blocks/CU * 256 CUs.
static __device__ __forceinline__ void grid_bar(unsigned int* bar, int slot) {
    __syncthreads();
    if (threadIdx.x == 0) {
        __hip_atomic_fetch_add(&bar[slot], 1u, __ATOMIC_ACQ_REL, __HIP_MEMORY_SCOPE_AGENT);
        for (int it = 0; it < (1 << 21); ++it) {   // cap: hang-proof backstop, never expected
            if (__hip_atomic_load(&bar[slot], __ATOMIC_ACQUIRE, __HIP_MEMORY_SCOPE_AGENT) >= NBLK)
                break;
            __builtin_amdgcn_s_sleep(8);
        }
    }
    __syncthreads();
}

// h = relu(W1 f + b1); out = relu(W2 h + b2)
static __device__ __forceinline__ float mlp3(float f0, float f1, float f2, const float* w) {
    float h0 = fmaxf(w[0]*f0 + w[1]*f1 + w[2]*f2 + w[9],  0.0f);
    float h1 = fmaxf(w[3]*f0 + w[4]*f1 + w[5]*f2 + w[10], 0.0f);
    float h2 = fmaxf(w[6]*f0 + w[7]*f1 + w[8]*f2 + w[11], 0.0f);
    return fmaxf(w[12]*h0 + w[13]*h1 + w[14]*h2 + w[15], 0.0f);
}
static __device__ __forceinline__ float ahnew_calc(float ah, float grad, float uuv, const float* w) {
    float va = mlp3(ah, grad, uuv, w);
    float vr = mlp3(ah, grad, uuv, w + 16);
    float v = fmaxf(fabsf(va) - vr, 0.0f);
    return fminf(v, 1.0f);
}

__global__ __launch_bounds__(256, 4) void k_main(
        const float* __restrict__ u, const float* __restrict__ x,
        float* __restrict__ rs, unsigned int* __restrict__ bar,
        float* __restrict__ out,
        const float* __restrict__ aW1, const float* __restrict__ ab1,
        const float* __restrict__ aW2, const float* __restrict__ ab2,
        const float* __restrict__ rW1, const float* __restrict__ rb1,
        const float* __restrict__ rW2, const float* __restrict__ rb2,
        const float* __restrict__ lW1, const float* __restrict__ lb1,
        const float* __restrict__ lW2, const float* __restrict__ lb2) {
    // LDS: 16640*2 + 2080 + 1024 + 512 + 512 + 128 = 37536 B -> guaranteed 4 blocks/CU
    __shared__ unsigned int stA[TILE * 65];   // packed state tile IJ (lo=uu, hi=ahat)
    __shared__ unsigned int stB[TILE * 65];   // packed state tile JI (diag: second tile)
    __shared__ float buf[8 * 65];             // offdiag: a_val 8-row chunk staging; diag: x of tile B
    __shared__ float xIl[4 * TILE];           // row-role x for I-tile
    __shared__ float lsI[TILE], lsJ[TILE];
    __shared__ float rsIb[TILE], rsJb[TILE];
    __shared__ float w[32];

    int gid = blockIdx.x, tid = threadIdx.x;
    int c = tid & 63, rg = tid >> 6;
    float lam = 0.0f;   // lambda recurrence register (tid<128 only)

    if (gid < BB * NOFF) {
        // ================= off-diagonal pair =================
        int b = gid / NOFF, po = gid % NOFF;
        int i = 0; while (po >= NTILE - 1 - i) { po -= NTILE - 1 - i; i++; }
        int Ib = i * TILE, Jb = (i + 1 + po) * TILE;

        float xc0 = x[((size_t)b*LL + Jb + c)*4 + 0], xc1 = x[((size_t)b*LL + Jb + c)*4 + 1];
        float xc2 = x[((size_t)b*LL + Jb + c)*4 + 2], xc3 = x[((size_t)b*LL + Jb + c)*4 + 3];
        float bu_c = xc1, bg_c = xc3, s1_c = xc0 + xc3, s2_c = xc2 + xc1;
        { int row = tid >> 2, k2 = tid & 3;
          xIl[k2*TILE + row] = x[((size_t)b*LL + Ib + row)*4 + k2]; }

        // ---- init: u -> packed LDS state ----
        size_t ubIJ = ((size_t)b*LL + Ib)*LL + Jb;
        size_t ubJI = ((size_t)b*LL + Jb)*LL + Ib;
        #pragma unroll
        for (int k = 0; k < 16; k++) {
            int r = rg + 4*k;
            float uv  = u[ubIJ + (size_t)r*LL + c];
            float uuv = sigm(2.0f*(uv - S_CONST))*uv;
            float ah  = sigm(uuv)*sigm(2.0f*(uuv - S_CONST));
            stA[r*65 + c] = pk2(uuv, ah);
            uv  = u[ubJI + (size_t)r*LL + c];
            uuv = sigm(2.0f*(uv - S_CONST))*uv;
            ah  = sigm(uuv)*sigm(2.0f*(uuv - S_CONST));
            stB[r*65 + c] = pk2(uuv, ah);
        }
        if (tid < 64) rsIb[tid] = 0.0f; else if (tid < 128) rsJb[tid-64] = 0.0f;
        __syncthreads();

        // ---- rowsums of a0 (8-row chunks) ----
        {
            float rsJacc = 0.0f;
            for (int q = 0; q < 8; q++) {
                #pragma unroll
                for (int kk = 0; kk < 2; kk++) {
                    int jj = 4*kk + rg, r = 8*q + jj;
                    float ah_ij = hi2f(stA[r*65 + c]);
                    float ah_ji = hi2f(stB[c*65 + r]);
                    float m = xIl[0*TILE+r]*bu_c + xIl[2*TILE+r]*bg_c
                            + xIl[1*TILE+r]*s1_c + xIl[3*TILE+r]*s2_c;
                    float a0 = 0.5f*(ah_ij*ah_ij + ah_ji*ah_ji)*m;
                    buf[jj*65 + c] = a0;
                    rsJacc += a0;
                }
                __syncthreads();
                { int jj = tid & 7, rowb = tid >> 3;
                  float acc = buf[jj*65 + rowb] + buf[jj*65 + rowb + 32];
                  atomicAdd(&rsIb[8*q + jj], acc); }
                __syncthreads();
            }
            atomicAdd(&rsJb[c], rsJacc);
            __syncthreads();
            if (tid < 64) atomicAdd(&rs[b*LL + Ib + tid], rsIb[tid]);
            else if (tid < 128) atomicAdd(&rs[b*LL + Jb + (tid-64)], rsJb[tid-64]);
        }
        grid_bar(bar, 0);

        // ---- time loop; state stays in LDS ----
        for (int t = 0; t < TT; t++) {
            const float* rs_cur = rs + (size_t)t*BB*LL;
            if (tid < 128) {
                int row = (tid < 64) ? (Ib + tid) : (Jb + tid - 64);
                float rsv = __hip_atomic_load(&rs_cur[b*LL + row], __ATOMIC_RELAXED, __HIP_MEMORY_SCOPE_AGENT);
                float lg = fmaxf(rsv - 1.0f, 0.0f);
                if (t == 0) lam = lg;
                else {
                    int o = t - 1;
                    float h0 = fmaxf(lW1[o*6+0]*lam + lW1[o*6+1]*lg + lb1[o*3+0], 0.0f);
                    float h1 = fmaxf(lW1[o*6+2]*lam + lW1[o*6+3]*lg + lb1[o*3+1], 0.0f);
                    float h2 = fmaxf(lW1[o*6+4]*lam + lW1[o*6+5]*lg + lb1[o*3+2], 0.0f);
                    lam = fmaxf(lW2[o*3+0]*h0 + lW2[o*3+1]*h1 + lW2[o*3+2]*h2 + lb2[o], 0.0f);
                }
                float lsv = lam * sigm(2.0f*(rsv - 1.0f));
                if (tid < 64) { lsI[tid] = lsv; rsIb[tid] = 0.0f; }
                else          { lsJ[tid-64] = lsv; rsJb[tid-64] = 0.0f; }
            }
            if (tid < 32) {
                float v;
                if      (tid <  9) v = aW1[t*9 + tid];
                else if (tid < 12) v = ab1[t*3 + (tid-9)];
                else if (tid < 15) v = aW2[t*3 + (tid-12)];
                else if (tid < 16) v = ab2[t];
                else if (tid < 25) v = rW1[t*9 + (tid-16)];
                else if (tid < 28) v = rb1[t*3 + (tid-25)];
                else if (tid < 31) v = rW2[t*3 + (tid-28)];
                else               v = rb2[t];
                w[tid] = v;
            }
            __syncthreads();

            size_t outBase = (((size_t)t*BB + b)*LL)*LL;
            bool last = (t == TT-1);
            float* rs_next = rs + (size_t)(t+1)*BB*LL;   // unused at last t
            float rsJacc = 0.0f;
            for (int q = 0; q < 8; q++) {
                #pragma unroll
                for (int kk = 0; kk < 2; kk++) {
                    int jj = 4*kk + rg, r = 8*q + jj;
                    unsigned int vA = stA[r*65 + c], vB = stB[c*65 + r];  // thread-private slots
                    float uu_ij = lo2f(vA), ah_ij = hi2f(vA);
                    float uu_ji = lo2f(vB), ah_ji = hi2f(vB);
                    float m = xIl[0*TILE+r]*bu_c + xIl[2*TILE+r]*bg_c
                            + xIl[1*TILE+r]*s1_c + xIl[3*TILE+r]*s2_c;
                    float gsum = -0.5f*(uu_ij + uu_ji) + lsI[r] + lsJ[c];
                    float an_ij = ahnew_calc(ah_ij, ah_ij*m*gsum, uu_ij, w);
                    float an_ji = ahnew_calc(ah_ji, ah_ji*m*gsum, uu_ji, w);
                    float a_val = 0.5f*(an_ij*an_ij + an_ji*an_ji)*m;
                    ((unsigned short*)stA)[(r*65 + c)*2 + 1] = f2bf(an_ij);
                    ((unsigned short*)stB)[(c*65 + r)*2 + 1] = f2bf(an_ji);
                    __builtin_nontemporal_store(a_val, &out[outBase + (size_t)(Ib+r)*LL + (Jb+c)]);
                    buf[jj*65 + c] = a_val;
                    rsJacc += a_val;
                }
                __syncthreads();
                { int jj = tid & 7, rowb = tid >> 3;
                  float acc = 0.0f;
                  #pragma unroll
                  for (int s = 0; s < 2; s++) {
                      int row = rowb + 32*s;
                      float v = buf[jj*65 + row];
                      __builtin_nontemporal_store(v, &out[outBase + (size_t)(Jb+row)*LL + (Ib + 8*q + jj)]);
                      acc += v;
                  }
                  if (!last) atomicAdd(&rsIb[8*q + jj], acc); }
                __syncthreads();
            }
            if (!last) {
                atomicAdd(&rsJb[c], rsJacc);
                __syncthreads();
                if (tid < 64) atomicAdd(&rs_next[b*LL + Ib + tid], rsIb[tid]);
                else if (tid < 128) atomicAdd(&rs_next[b*LL + Jb + (tid-64)], rsJb[tid-64]);
                grid_bar(bar, 1 + t);
            }
        }
    } else {
        // ================= merged diagonal block: two diag tiles =================
        int d = gid - BB*NOFF;          // 0..63
        int g0 = 2*d;
        int b = g0 >> 4;
        int Ab = (g0 & 15) * TILE, Bb = ((g0 & 15) + 1) * TILE;
        float* xIlB = buf;              // diag never uses the staging buffer (needs 1024B <= 2080B)

        float t0, t1, t2, t3;
        t0 = x[((size_t)b*LL + Ab + c)*4 + 0]; t1 = x[((size_t)b*LL + Ab + c)*4 + 1];
        t2 = x[((size_t)b*LL + Ab + c)*4 + 2]; t3 = x[((size_t)b*LL + Ab + c)*4 + 3];
        float buA = t1, bgA = t3, s1A = t0 + t3, s2A = t2 + t1;
        t0 = x[((size_t)b*LL + Bb + c)*4 + 0]; t1 = x[((size_t)b*LL + Bb + c)*4 + 1];
        t2 = x[((size_t)b*LL + Bb + c)*4 + 2]; t3 = x[((size_t)b*LL + Bb + c)*4 + 3];
        float buB = t1, bgB = t3, s1B = t0 + t3, s2B = t2 + t1;
        { int row = tid >> 2, k2 = tid & 3;
          xIl [k2*TILE + row] = x[((size_t)b*LL + Ab + row)*4 + k2];
          xIlB[k2*TILE + row] = x[((size_t)b*LL + Bb + row)*4 + k2]; }

        size_t ubA = ((size_t)b*LL + Ab)*LL + Ab;
        size_t ubB = ((size_t)b*LL + Bb)*LL + Bb;
        #pragma unroll
        for (int k = 0; k < 16; k++) {
            int r = rg + 4*k;
            float uv  = u[ubA + (size_t)r*LL + c];
            float uuv = sigm(2.0f*(uv - S_CONST))*uv;
            float ah  = sigm(uuv)*sigm(2.0f*(uuv - S_CONST));
            stA[r*65 + c] = pk2(uuv, ah);
            uv  = u[ubB + (size_t)r*LL + c];
            uuv = sigm(2.0f*(uv - S_CONST))*uv;
            ah  = sigm(uuv)*sigm(2.0f*(uuv - S_CONST));
            stB[r*65 + c] = pk2(uuv, ah);
        }
        if (tid < 64) rsIb[tid] = 0.0f; else if (tid < 128) rsJb[tid-64] = 0.0f;
        __syncthreads();
        {
            float accA = 0.0f, accB = 0.0f;
            #pragma unroll
            for (int k = 0; k < 16; k++) {
                int r = rg + 4*k;
                float aij = hi2f(stA[r*65 + c]), aji = hi2f(stA[c*65 + r]);
                float m = xIl[0*TILE+r]*buA + xIl[2*TILE+r]*bgA
                        + xIl[1*TILE+r]*s1A + xIl[3*TILE+r]*s2A;
                accA += 0.5f*(aij*aij + aji*aji)*m;
                aij = hi2f(stB[r*65 + c]); aji = hi2f(stB[c*65 + r]);
                m = xIlB[0*TILE+r]*buB + xIlB[2*TILE+r]*bgB
                  + xIlB[1*TILE+r]*s1B + xIlB[3*TILE+r]*s2B;
                accB += 0.5f*(aij*aij + aji*aji)*m;
            }
            atomicAdd(&rsIb[c], accA);
            atomicAdd(&rsJb[c], accB);
            __syncthreads();
            if (tid < 64) atomicAdd(&rs[b*LL + Ab + tid], rsIb[tid]);
            else if (tid < 128) atomicAdd(&rs[b*LL + Bb + (tid-64)], rsJb[tid-64]);
        }
        grid_bar(bar, 0);

        for (int t = 0; t < TT; t++) {
            const float* rs_cur = rs + (size_t)t*BB*LL;
            if (tid < 128) {
                int row = (tid < 64) ? (Ab + tid) : (Bb + tid - 64);
                float rsv = __hip_atomic_load(&rs_cur[b*LL + row], __ATOMIC_RELAXED, __HIP_MEMORY_SCOPE_AGENT);
                float lg = fmaxf(rsv - 1.0f, 0.0f);
                if (t == 0) lam = lg;
                else {
                    int o = t - 1;
                    float h0 = fmaxf(lW1[o*6+0]*lam + lW1[o*6+1]*lg + lb1[o*3+0], 0.0f);
                    float h1 = fmaxf(lW1[o*6+2]*lam + lW1[o*6+3]*lg + lb1[o*3+1], 0.0f);
                    float h2 = fmaxf(lW1[o*6+4]*lam + lW1[o*6+5]*lg + lb1[o*3+2], 0.0f);
                    lam = fmaxf(lW2[o*3+0]*h0 + lW2[o*3+1]*h1 + lW2[o*3+2]*h2 + lb2[o], 0.0f);
                }
                float lsv = lam * sigm(2.0f*(rsv - 1.0f));
                if (tid < 64) { lsI[tid] = lsv; rsIb[tid] = 0.0f; }
                else          { lsJ[tid-64] = lsv; rsJb[tid-64] = 0.0f; }
            }
            if (tid < 32) {
                float v;
                if      (tid <  9) v = aW1[t*9 + tid];
                else if (tid < 12) v = ab1[t*3 + (tid-9)];
                else if (tid < 15) v = aW2[t*3 + (tid-12)];
                else if (tid < 16) v = ab2[t];
                else if (tid < 25) v = rW1[t*9 + (tid-16)];
                else if (tid < 28) v = rb1[t*3 + (tid-25)];
                else if (tid < 31) v = rW2[t*3 + (tid-28)];
                else               v = rb2[t];
                w[tid] = v;
            }
            __syncthreads();

            size_t outBase = (((size_t)t*BB + b)*LL)*LL;
            bool last = (t == TT-1);
            float* rs_next = rs + (size_t)(t+1)*BB*LL;

            // ---- tile A: stage transposed old state first (read-before-write) ----
            unsigned int vT[16];
            #pragma unroll
            for (int k = 0; k < 16; k++) vT[k] = stA[c*65 + (rg + 4*k)];
            __syncthreads();
            float acc = 0.0f;
            #pragma unroll
            for (int k = 0; k < 16; k++) {
                int r = rg + 4*k;
                unsigned int vO = stA[r*65 + c];
                float uu_ij = lo2f(vO), ah_ij = hi2f(vO);
                float uu_ji = lo2f(vT[k]), ah_ji = hi2f(vT[k]);
                float m = xIl[0*TILE+r]*buA + xIl[2*TILE+r]*bgA
                        + xIl[1*TILE+r]*s1A + xIl[3*TILE+r]*s2A;
                float gsum = -0.5f*(uu_ij + uu_ji) + lsI[r] + lsI[c];
                float an_ij = ahnew_calc(ah_ij, ah_ij*m*gsum, uu_ij, w);
                float an_ji = ahnew_calc(ah_ji, ah_ji*m*gsum, uu_ji, w);
                float a_val = 0.5f*(an_ij*an_ij + an_ji*an_ji)*m;
                ((unsigned short*)stA)[(r*65 + c)*2 + 1] = f2bf(an_ij);   // own slot only
                __builtin_nontemporal_store(a_val, &out[outBase + (size_t)(Ab+r)*LL + (Ab+c)]);
                acc += a_val;
            }
            if (!last) atomicAdd(&rsIb[c], acc);

            // ---- tile B ----
            #pragma unroll
            for (int k = 0; k < 16; k++) vT[k] = stB[c*65 + (rg + 4*k)];
            __syncthreads();
            acc = 0.0f;
            #pragma unroll
            for (int k = 0; k < 16; k++) {
                int r = rg + 4*k;
                unsigned int vO = stB[r*65 + c];
                float uu_ij = lo2f(vO), ah_ij = hi2f(vO);
                float uu_ji = lo2f(vT[k]), ah_ji = hi2f(vT[k]);
                float m = xIlB[0*TILE+r]*buB + xIlB[2*TILE+r]*bgB
                        + xIlB[1*TILE+r]*s1B + xIlB[3*TILE+r]*s2B;
                float gsum = -0.5f*(uu_ij + uu_ji) + lsJ[r] + lsJ[c];
                float an_ij = ahnew_calc(ah_ij, ah_ij*m*gsum, uu_ij, w);
                float an_ji = ahnew_calc(ah_ji, ah_ji*m*gsum, uu_ji, w);
                float a_val = 0.5f*(an_ij*an_ij + an_ji*an_ji)*m;
                ((unsigned short*)stB)[(r*65 + c)*2 + 1] = f2bf(an_ij);
                __builtin_nontemporal_store(a_val, &out[outBase + (size_t)(Bb+r)*LL + (Bb+c)]);
                acc += a_val;
            }
            if (!last) {
                atomicAdd(&rsJb[c], acc);
                __syncthreads();
                if (tid < 64) atomicAdd(&rs_next[b*LL + Ab + tid], rsIb[tid]);
                else if (tid < 128) atomicAdd(&rs_next[b*LL + Bb + (tid-64)], rsJb[tid-64]);
                grid_bar(bar, 1 + t);
            }
        }
    }
}

extern "C" void kernel_launch(void* const* d_in, const int* in_sizes, int n_in,
                              void* d_out, int out_size, void* d_ws, size_t ws_size,
                              hipStream_t stream) {
    const float* u   = (const float*)d_in[0];
    const float* x   = (const float*)d_in[1];
    const float* aW1 = (const float*)d_in[3];
    const float* ab1 = (const float*)d_in[4];
    const float* aW2 = (const float*)d_in[5];
    const float* ab2 = (const float*)d_in[6];
    const float* rW1 = (const float*)d_in[7];
    const float* rb1 = (const float*)d_in[8];
    const float* rW2 = (const float*)d_in[9];
    const float* rb2 = (const float*)d_in[10];
    const float* lW1 = (const float*)d_in[11];
    const float* lb1 = (const float*)d_in[12];
    const float* lW2 = (const float*)d_in[13];
    const float* lb2 = (const float*)d_in[14];
    float* out = (float*)d_out;

    float* rs = (float*)d_ws;                          // TT rowsum buffers
    unsigned int* bar = (unsigned int*)(rs + (size_t)TT * BB * LL);  // 16 barrier slots
    hipMemsetAsync(rs, 0, (size_t)TT * BB * LL * sizeof(float) + 16 * sizeof(unsigned int), stream);

    hipLaunchKernelGGL(k_main, dim3(NBLK), dim3(256), 0, stream,
                       u, x, rs, bar, out,
                       aW1, ab1, aW2, ab2, rW1, rb1, rW2, rb2,
                       lW1, lb1, lW2, lb2);
}

// Round 4
// 1270.012 us; speedup vs baseline: 1.4135x; 1.4135x over previous
//
#include <hip/hip_runtime.h>
#include <hip/hip_bf16.h>

#define BB 8
#define LL 1024
#define TT 10
#define TILE 64
#define NTILE 16
#define NOFF 120                 // off-diag pairs per batch (I<J)
#define NBLK 1024                // 960 offdiag + 64 merged-diag = exactly 4/CU
#define S_CONST 2.1972245773362196f

typedef __hip_bfloat16 bf16;

static __device__ __forceinline__ float sigm(float v) {
    return 1.0f / (1.0f + __expf(-v));
}
static __device__ __forceinline__ unsigned short f2bf(float v) {
    bf16 h = __float2bfloat16(v);   // RNE, same rounding as round-1 (passing)
    unsigned short b; __builtin_memcpy(&b, &h, 2); return b;
}
static __device__ __forceinline__ float lo2f(unsigned int v) { return __uint_as_float(v << 16); }
static __device__ __forceinline__ float hi2f(unsigned int v) { return __uint_as_float(v & 0xffff0000u); }
static __device__ __forceinline__ unsigned int pk2(float uu, float ah) {
    return (unsigned int)f2bf(uu) | ((unsigned int)f2bf(ah) << 16);
}

// Manual grid barrier, FULLY RELAXED atomics (no buffer_inv/wbl2 cache maintenance).
// Ordering argument: each wave's rs atomicAdds are drained by the s_waitcnt vmcnt(0)
// the compiler emits before s_barrier (__syncthreads). The arrival add is therefore
// issued after all this block's rs adds completed at the coherence point. All
// cross-block data (rs) is read/written exclusively with agent-scope atomics, which
// bypass the non-coherent L1/L2 — so no invalidate is needed on the consumer side.
// Co-residency of all NBLK blocks is guaranteed by resource math:
// LDS 37536B (<40KiB) and VGPR<=128 (launch_bounds) -> exactly 4 blocks/CU * 256 CUs.
static __device__ __forceinline__ void grid_bar(unsigned int* bar, int slot) {
    __syncthreads();
    if (threadIdx.x == 0) {
        __hip_atomic_fetch_add(&bar[slot], 1u, __ATOMIC_RELAXED, __HIP_MEMORY_SCOPE_AGENT);
        for (int it = 0; it < (1 << 21); ++it) {   // cap: hang-proof backstop, never expected
            if (__hip_atomic_load(&bar[slot], __ATOMIC_RELAXED, __HIP_MEMORY_SCOPE_AGENT) >= NBLK)
                break;
            __builtin_amdgcn_s_sleep(8);
        }
    }
    __syncthreads();
}

// h = relu(W1 f + b1); out = relu(W2 h + b2)
static __device__ __forceinline__ float mlp3(float f0, float f1, float f2, const float* w) {
    float h0 = fmaxf(w[0]*f0 + w[1]*f1 + w[2]*f2 + w[9],  0.0f);
    float h1 = fmaxf(w[3]*f0 + w[4]*f1 + w[5]*f2 + w[10], 0.0f);
    float h2 = fmaxf(w[6]*f0 + w[7]*f1 + w[8]*f2 + w[11], 0.0f);
    return fmaxf(w[12]*h0 + w[13]*h1 + w[14]*h2 + w[15], 0.0f);
}
static __device__ __forceinline__ float ahnew_calc(float ah, float grad, float uuv, const float* w) {
    float va = mlp3(ah, grad, uuv, w);
    float vr = mlp3(ah, grad, uuv, w + 16);
    float v = fmaxf(fabsf(va) - vr, 0.0f);
    return fminf(v, 1.0f);
}

// load step-t MLP weights into shared w[32] (prefetched BEFORE the grid barrier)
#define LOAD_W(tt) do { if (tid < 32) { int _t = (tt); float v; \
    if      (tid <  9) v = aW1[_t*9 + tid]; \
    else if (tid < 12) v = ab1[_t*3 + (tid-9)]; \
    else if (tid < 15) v = aW2[_t*3 + (tid-12)]; \
    else if (tid < 16) v = ab2[_t]; \
    else if (tid < 25) v = rW1[_t*9 + (tid-16)]; \
    else if (tid < 28) v = rb1[_t*3 + (tid-25)]; \
    else if (tid < 31) v = rW2[_t*3 + (tid-28)]; \
    else               v = rb2[_t]; \
    w[tid] = v; } } while (0)

__global__ __launch_bounds__(256, 4) void k_main(
        const float* __restrict__ u, const float* __restrict__ x,
        float* __restrict__ rs, unsigned int* __restrict__ bar,
        float* __restrict__ out,
        const float* __restrict__ aW1, const float* __restrict__ ab1,
        const float* __restrict__ aW2, const float* __restrict__ ab2,
        const float* __restrict__ rW1, const float* __restrict__ rb1,
        const float* __restrict__ rW2, const float* __restrict__ rb2,
        const float* __restrict__ lW1, const float* __restrict__ lb1,
        const float* __restrict__ lW2, const float* __restrict__ lb2) {
    // LDS: 16640*2 + 2080 + 1024 + 512 + 512 + 128 = 37536 B -> guaranteed 4 blocks/CU
    __shared__ unsigned int stA[TILE * 65];   // packed state tile IJ (lo=uu, hi=ahat)
    __shared__ unsigned int stB[TILE * 65];   // packed state tile JI (diag: second tile)
    __shared__ float buf[8 * 65];             // offdiag: a_val 8-row chunk staging; diag: x of tile B
    __shared__ float xIl[4 * TILE];           // row-role x for I-tile
    __shared__ float lsI[TILE], lsJ[TILE];
    __shared__ float rsIb[TILE], rsJb[TILE];
    __shared__ float w[32];

    int gid = blockIdx.x, tid = threadIdx.x;
    int c = tid & 63, rg = tid >> 6;
    float lam = 0.0f;   // lambda recurrence register (tid<128 only)

    if (gid < BB * NOFF) {
        // ================= off-diagonal pair =================
        int b = gid / NOFF, po = gid % NOFF;
        int i = 0; while (po >= NTILE - 1 - i) { po -= NTILE - 1 - i; i++; }
        int Ib = i * TILE, Jb = (i + 1 + po) * TILE;

        float xc0 = x[((size_t)b*LL + Jb + c)*4 + 0], xc1 = x[((size_t)b*LL + Jb + c)*4 + 1];
        float xc2 = x[((size_t)b*LL + Jb + c)*4 + 2], xc3 = x[((size_t)b*LL + Jb + c)*4 + 3];
        float bu_c = xc1, bg_c = xc3, s1_c = xc0 + xc3, s2_c = xc2 + xc1;
        { int row = tid >> 2, k2 = tid & 3;
          xIl[k2*TILE + row] = x[((size_t)b*LL + Ib + row)*4 + k2]; }

        // ---- init: u -> packed LDS state ----
        size_t ubIJ = ((size_t)b*LL + Ib)*LL + Jb;
        size_t ubJI = ((size_t)b*LL + Jb)*LL + Ib;
        #pragma unroll
        for (int k = 0; k < 16; k++) {
            int r = rg + 4*k;
            float uv  = u[ubIJ + (size_t)r*LL + c];
            float uuv = sigm(2.0f*(uv - S_CONST))*uv;
            float ah  = sigm(uuv)*sigm(2.0f*(uuv - S_CONST));
            stA[r*65 + c] = pk2(uuv, ah);
            uv  = u[ubJI + (size_t)r*LL + c];
            uuv = sigm(2.0f*(uv - S_CONST))*uv;
            ah  = sigm(uuv)*sigm(2.0f*(uuv - S_CONST));
            stB[r*65 + c] = pk2(uuv, ah);
        }
        if (tid < 64) rsIb[tid] = 0.0f; else if (tid < 128) rsJb[tid-64] = 0.0f;
        __syncthreads();

        // ---- rowsums of a0 (8-row chunks) ----
        {
            float rsJacc = 0.0f;
            for (int q = 0; q < 8; q++) {
                #pragma unroll
                for (int kk = 0; kk < 2; kk++) {
                    int jj = 4*kk + rg, r = 8*q + jj;
                    float ah_ij = hi2f(stA[r*65 + c]);
                    float ah_ji = hi2f(stB[c*65 + r]);
                    float m = xIl[0*TILE+r]*bu_c + xIl[2*TILE+r]*bg_c
                            + xIl[1*TILE+r]*s1_c + xIl[3*TILE+r]*s2_c;
                    float a0 = 0.5f*(ah_ij*ah_ij + ah_ji*ah_ji)*m;
                    buf[jj*65 + c] = a0;
                    rsJacc += a0;
                }
                __syncthreads();
                { int jj = tid & 7, rowb = tid >> 3;
                  float acc = buf[jj*65 + rowb] + buf[jj*65 + rowb + 32];
                  atomicAdd(&rsIb[8*q + jj], acc); }
                __syncthreads();
            }
            atomicAdd(&rsJb[c], rsJacc);
            __syncthreads();
            if (tid < 64) atomicAdd(&rs[b*LL + Ib + tid], rsIb[tid]);
            else if (tid < 128) atomicAdd(&rs[b*LL + Jb + (tid-64)], rsJb[tid-64]);
        }
        LOAD_W(0);                      // prefetch step-0 weights before the barrier
        grid_bar(bar, 0);

        // ---- time loop; state stays in LDS ----
        for (int t = 0; t < TT; t++) {
            const float* rs_cur = rs + (size_t)t*BB*LL;
            if (tid < 128) {
                int row = (tid < 64) ? (Ib + tid) : (Jb + tid - 64);
                float rsv = __hip_atomic_load(&rs_cur[b*LL + row], __ATOMIC_RELAXED, __HIP_MEMORY_SCOPE_AGENT);
                float lg = fmaxf(rsv - 1.0f, 0.0f);
                if (t == 0) lam = lg;
                else {
                    int o = t - 1;
                    float h0 = fmaxf(lW1[o*6+0]*lam + lW1[o*6+1]*lg + lb1[o*3+0], 0.0f);
                    float h1 = fmaxf(lW1[o*6+2]*lam + lW1[o*6+3]*lg + lb1[o*3+1], 0.0f);
                    float h2 = fmaxf(lW1[o*6+4]*lam + lW1[o*6+5]*lg + lb1[o*3+2], 0.0f);
                    lam = fmaxf(lW2[o*3+0]*h0 + lW2[o*3+1]*h1 + lW2[o*3+2]*h2 + lb2[o], 0.0f);
                }
                float lsv = lam * sigm(2.0f*(rsv - 1.0f));
                if (tid < 64) { lsI[tid] = lsv; rsIb[tid] = 0.0f; }
                else          { lsJ[tid-64] = lsv; rsJb[tid-64] = 0.0f; }
            }
            __syncthreads();

            size_t outBase = (((size_t)t*BB + b)*LL)*LL;
            bool last = (t == TT-1);
            float* rs_next = rs + (size_t)(t+1)*BB*LL;   // unused at last t
            float rsJacc = 0.0f;
            for (int q = 0; q < 8; q++) {
                #pragma unroll
                for (int kk = 0; kk < 2; kk++) {
                    int jj = 4*kk + rg, r = 8*q + jj;
                    unsigned int vA = stA[r*65 + c], vB = stB[c*65 + r];  // thread-private slots
                    float uu_ij = lo2f(vA), ah_ij = hi2f(vA);
                    float uu_ji = lo2f(vB), ah_ji = hi2f(vB);
                    float m = xIl[0*TILE+r]*bu_c + xIl[2*TILE+r]*bg_c
                            + xIl[1*TILE+r]*s1_c + xIl[3*TILE+r]*s2_c;
                    float gsum = -0.5f*(uu_ij + uu_ji) + lsI[r] + lsJ[c];
                    float an_ij = ahnew_calc(ah_ij, ah_ij*m*gsum, uu_ij, w);
                    float an_ji = ahnew_calc(ah_ji, ah_ji*m*gsum, uu_ji, w);
                    float a_val = 0.5f*(an_ij*an_ij + an_ji*an_ji)*m;
                    ((unsigned short*)stA)[(r*65 + c)*2 + 1] = f2bf(an_ij);
                    ((unsigned short*)stB)[(c*65 + r)*2 + 1] = f2bf(an_ji);
                    __builtin_nontemporal_store(a_val, &out[outBase + (size_t)(Ib+r)*LL + (Jb+c)]);
                    buf[jj*65 + c] = a_val;
                    rsJacc += a_val;
                }
                __syncthreads();
                { int jj = tid & 7, rowb = tid >> 3;
                  float acc = 0.0f;
                  #pragma unroll
                  for (int s = 0; s < 2; s++) {
                      int row = rowb + 32*s;
                      float v = buf[jj*65 + row];
                      __builtin_nontemporal_store(v, &out[outBase + (size_t)(Jb+row)*LL + (Ib + 8*q + jj)]);
                      acc += v;
                  }
                  if (!last) atomicAdd(&rsIb[8*q + jj], acc); }
                __syncthreads();
            }
            if (!last) {
                atomicAdd(&rsJb[c], rsJacc);
                __syncthreads();
                if (tid < 64) atomicAdd(&rs_next[b*LL + Ib + tid], rsIb[tid]);
                else if (tid < 128) atomicAdd(&rs_next[b*LL + Jb + (tid-64)], rsJb[tid-64]);
                LOAD_W(t+1);            // prefetch next-step weights before the barrier
                grid_bar(bar, 1 + t);
            }
        }
    } else {
        // ================= merged diagonal block: two diag tiles =================
        int d = gid - BB*NOFF;          // 0..63
        int g0 = 2*d;
        int b = g0 >> 4;
        int Ab = (g0 & 15) * TILE, Bb = ((g0 & 15) + 1) * TILE;
        float* xIlB = buf;              // diag never uses the staging buffer (needs 1024B <= 2080B)

        float t0, t1, t2, t3;
        t0 = x[((size_t)b*LL + Ab + c)*4 + 0]; t1 = x[((size_t)b*LL + Ab + c)*4 + 1];
        t2 = x[((size_t)b*LL + Ab + c)*4 + 2]; t3 = x[((size_t)b*LL + Ab + c)*4 + 3];
        float buA = t1, bgA = t3, s1A = t0 + t3, s2A = t2 + t1;
        t0 = x[((size_t)b*LL + Bb + c)*4 + 0]; t1 = x[((size_t)b*LL + Bb + c)*4 + 1];
        t2 = x[((size_t)b*LL + Bb + c)*4 + 2]; t3 = x[((size_t)b*LL + Bb + c)*4 + 3];
        float buB = t1, bgB = t3, s1B = t0 + t3, s2B = t2 + t1;
        { int row = tid >> 2, k2 = tid & 3;
          xIl [k2*TILE + row] = x[((size_t)b*LL + Ab + row)*4 + k2];
          xIlB[k2*TILE + row] = x[((size_t)b*LL + Bb + row)*4 + k2]; }

        size_t ubA = ((size_t)b*LL + Ab)*LL + Ab;
        size_t ubB = ((size_t)b*LL + Bb)*LL + Bb;
        #pragma unroll
        for (int k = 0; k < 16; k++) {
            int r = rg + 4*k;
            float uv  = u[ubA + (size_t)r*LL + c];
            float uuv = sigm(2.0f*(uv - S_CONST))*uv;
            float ah  = sigm(uuv)*sigm(2.0f*(uuv - S_CONST));
            stA[r*65 + c] = pk2(uuv, ah);
            uv  = u[ubB + (size_t)r*LL + c];
            uuv = sigm(2.0f*(uv - S_CONST))*uv;
            ah  = sigm(uuv)*sigm(2.0f*(uuv - S_CONST));
            stB[r*65 + c] = pk2(uuv, ah);
        }
        if (tid < 64) rsIb[tid] = 0.0f; else if (tid < 128) rsJb[tid-64] = 0.0f;
        __syncthreads();
        {
            float accA = 0.0f, accB = 0.0f;
            #pragma unroll
            for (int k = 0; k < 16; k++) {
                int r = rg + 4*k;
                float aij = hi2f(stA[r*65 + c]), aji = hi2f(stA[c*65 + r]);
                float m = xIl[0*TILE+r]*buA + xIl[2*TILE+r]*bgA
                        + xIl[1*TILE+r]*s1A + xIl[3*TILE+r]*s2A;
                accA += 0.5f*(aij*aij + aji*aji)*m;
                aij = hi2f(stB[r*65 + c]); aji = hi2f(stB[c*65 + r]);
                m = xIlB[0*TILE+r]*buB + xIlB[2*TILE+r]*bgB
                  + xIlB[1*TILE+r]*s1B + xIlB[3*TILE+r]*s2B;
                accB += 0.5f*(aij*aij + aji*aji)*m;
            }
            atomicAdd(&rsIb[c], accA);
            atomicAdd(&rsJb[c], accB);
            __syncthreads();
            if (tid < 64) atomicAdd(&rs[b*LL + Ab + tid], rsIb[tid]);
            else if (tid < 128) atomicAdd(&rs[b*LL + Bb + (tid-64)], rsJb[tid-64]);
        }
        LOAD_W(0);
        grid_bar(bar, 0);

        for (int t = 0; t < TT; t++) {
            const float* rs_cur = rs + (size_t)t*BB*LL;
            if (tid < 128) {
                int row = (tid < 64) ? (Ab + tid) : (Bb + tid - 64);
                float rsv = __hip_atomic_load(&rs_cur[b*LL + row], __ATOMIC_RELAXED, __HIP_MEMORY_SCOPE_AGENT);
                float lg = fmaxf(rsv - 1.0f, 0.0f);
                if (t == 0) lam = lg;
                else {
                    int o = t - 1;
                    float h0 = fmaxf(lW1[o*6+0]*lam + lW1[o*6+1]*lg + lb1[o*3+0], 0.0f);
                    float h1 = fmaxf(lW1[o*6+2]*lam + lW1[o*6+3]*lg + lb1[o*3+1], 0.0f);
                    float h2 = fmaxf(lW1[o*6+4]*lam + lW1[o*6+5]*lg + lb1[o*3+2], 0.0f);
                    lam = fmaxf(lW2[o*3+0]*h0 + lW2[o*3+1]*h1 + lW2[o*3+2]*h2 + lb2[o], 0.0f);
                }
                float lsv = lam * sigm(2.0f*(rsv - 1.0f));
                if (tid < 64) { lsI[tid] = lsv; rsIb[tid] = 0.0f; }
                else          { lsJ[tid-64] = lsv; rsJb[tid-64] = 0.0f; }
            }
            __syncthreads();

            size_t outBase = (((size_t)t*BB + b)*LL)*LL;
            bool last = (t == TT-1);
            float* rs_next = rs + (size_t)(t+1)*BB*LL;

            // ---- tile A: stage transposed old state first (read-before-write) ----
            unsigned int vT[16];
            #pragma unroll
            for (int k = 0; k < 16; k++) vT[k] = stA[c*65 + (rg + 4*k)];
            __syncthreads();
            float acc = 0.0f;
            #pragma unroll
            for (int k = 0; k < 16; k++) {
                int r = rg + 4*k;
                unsigned int vO = stA[r*65 + c];
                float uu_ij = lo2f(vO), ah_ij = hi2f(vO);
                float uu_ji = lo2f(vT[k]), ah_ji = hi2f(vT[k]);
                float m = xIl[0*TILE+r]*buA + xIl[2*TILE+r]*bgA
                        + xIl[1*TILE+r]*s1A + xIl[3*TILE+r]*s2A;
                float gsum = -0.5f*(uu_ij + uu_ji) + lsI[r] + lsI[c];
                float an_ij = ahnew_calc(ah_ij, ah_ij*m*gsum, uu_ij, w);
                float an_ji = ahnew_calc(ah_ji, ah_ji*m*gsum, uu_ji, w);
                float a_val = 0.5f*(an_ij*an_ij + an_ji*an_ji)*m;
                ((unsigned short*)stA)[(r*65 + c)*2 + 1] = f2bf(an_ij);   // own slot only
                __builtin_nontemporal_store(a_val, &out[outBase + (size_t)(Ab+r)*LL + (Ab+c)]);
                acc += a_val;
            }
            if (!last) atomicAdd(&rsIb[c], acc);

            // ---- tile B ----
            #pragma unroll
            for (int k = 0; k < 16; k++) vT[k] = stB[c*65 + (rg + 4*k)];
            __syncthreads();
            acc = 0.0f;
            #pragma unroll
            for (int k = 0; k < 16; k++) {
                int r = rg + 4*k;
                unsigned int vO = stB[r*65 + c];
                float uu_ij = lo2f(vO), ah_ij = hi2f(vO);
                float uu_ji = lo2f(vT[k]), ah_ji = hi2f(vT[k]);
                float m = xIlB[0*TILE+r]*buB + xIlB[2*TILE+r]*bgB
                        + xIlB[1*TILE+r]*s1B + xIlB[3*TILE+r]*s2B;
                float gsum = -0.5f*(uu_ij + uu_ji) + lsJ[r] + lsJ[c];
                float an_ij = ahnew_calc(ah_ij, ah_ij*m*gsum, uu_ij, w);
                float an_ji = ahnew_calc(ah_ji, ah_ji*m*gsum, uu_ji, w);
                float a_val = 0.5f*(an_ij*an_ij + an_ji*an_ji)*m;
                ((unsigned short*)stB)[(r*65 + c)*2 + 1] = f2bf(an_ij);
                __builtin_nontemporal_store(a_val, &out[outBase + (size_t)(Bb+r)*LL + (Bb+c)]);
                acc += a_val;
            }
            if (!last) {
                atomicAdd(&rsJb[c], acc);
                __syncthreads();
                if (tid < 64) atomicAdd(&rs_next[b*LL + Ab + tid], rsIb[tid]);
                else if (tid < 128) atomicAdd(&rs_next[b*LL + Bb + (tid-64)], rsJb[tid-64]);
                LOAD_W(t+1);
                grid_bar(bar, 1 + t);
            }
        }
    }
}

extern "C" void kernel_launch(void* const* d_in, const int* in_sizes, int n_in,
                              void* d_out, int out_size, void* d_ws, size_t ws_size,
                              hipStream_t stream) {
    const float* u   = (const float*)d_in[0];
    const float* x   = (const float*)d_in[1];
    const float* aW1 = (const float*)d_in[3];
    const float* ab1 = (const float*)d_in[4];
    const float* aW2 = (const float*)d_in[5];
    const float* ab2 = (const float*)d_in[6];
    const float* rW1 = (const float*)d_in[7];
    const float* rb1 = (const float*)d_in[8];
    const float* rW2 = (const float*)d_in[9];
    const float* rb2 = (const float*)d_in[10];
    const float* lW1 = (const float*)d_in[11];
    const float* lb1 = (const float*)d_in[12];
    const float* lW2 = (const float*)d_in[13];
    const float* lb2 = (const float*)d_in[14];
    float* out = (float*)d_out;

    float* rs = (float*)d_ws;                          // TT rowsum buffers
    unsigned int* bar = (unsigned int*)(rs + (size_t)TT * BB * LL);  // 16 barrier slots
    hipMemsetAsync(rs, 0, (size_t)TT * BB * LL * sizeof(float) + 16 * sizeof(unsigned int), stream);

    hipLaunchKernelGGL(k_main, dim3(NBLK), dim3(256), 0, stream,
                       u, x, rs, bar, out,
                       aW1, ab1, aW2, ab2, rW1, rb1, rW2, rb2,
                       lW1, lb1, lW2, lb2);
}

// Round 5
// 551.283 us; speedup vs baseline: 3.2564x; 2.3037x over previous
//
#include <hip/hip_runtime.h>
#include <hip/hip_bf16.h>

#define BB 8
#define LL 1024
#define TT 10
#define TILE 64
#define NTILE 16
#define NOFF 120                 // off-diag pairs per batch (I<J)
#define NBLK 1024                // 960 offdiag + 64 merged-diag = exactly 4/CU
#define S_CONST 2.1972245773362196f

typedef __hip_bfloat16 bf16;

static __device__ __forceinline__ float sigm(float v) {
    return 1.0f / (1.0f + __expf(-v));
}
static __device__ __forceinline__ unsigned short f2bf(float v) {
    bf16 h = __float2bfloat16(v);   // RNE, same rounding as round-1 (passing)
    unsigned short b; __builtin_memcpy(&b, &h, 2); return b;
}
static __device__ __forceinline__ float lo2f(unsigned int v) { return __uint_as_float(v << 16); }
static __device__ __forceinline__ float hi2f(unsigned int v) { return __uint_as_float(v & 0xffff0000u); }
static __device__ __forceinline__ unsigned int pk2(float uu, float ah) {
    return (unsigned int)f2bf(uu) | ((unsigned int)f2bf(ah) << 16);
}

// raw barrier: LDS ordering only (lgkmcnt), NO vmcnt drain — global stores stay in flight
#define RAWBAR() do { asm volatile("s_waitcnt lgkmcnt(0)" ::: "memory"); \
                      __builtin_amdgcn_s_barrier(); } while (0)

// fine-grained dependency: done[(t*128 + b*16 + tile)*16] counts producer blocks (16 per tile).
// Producers: rs atomicAdds -> per-wave s_waitcnt vmcnt(0) -> relaxed done add (release via ack).
// Consumers: poll done==16 -> rs values guaranteed at coherence point (all rs traffic is atomics).
static __device__ __forceinline__ void wait_done(const unsigned int* dcnt) {
    for (int it = 0; it < (1 << 20); ++it) {   // backstop only; never expected to trip
        if (__hip_atomic_load(dcnt, __ATOMIC_RELAXED, __HIP_MEMORY_SCOPE_AGENT) >= 16u)
            break;
        __builtin_amdgcn_s_sleep(4);
    }
}

// h = relu(W1 f + b1); out = relu(W2 h + b2)
static __device__ __forceinline__ float mlp3(float f0, float f1, float f2, const float* w) {
    float h0 = fmaxf(w[0]*f0 + w[1]*f1 + w[2]*f2 + w[9],  0.0f);
    float h1 = fmaxf(w[3]*f0 + w[4]*f1 + w[5]*f2 + w[10], 0.0f);
    float h2 = fmaxf(w[6]*f0 + w[7]*f1 + w[8]*f2 + w[11], 0.0f);
    return fmaxf(w[12]*h0 + w[13]*h1 + w[14]*h2 + w[15], 0.0f);
}
static __device__ __forceinline__ float ahnew_calc(float ah, float grad, float uuv, const float* w) {
    float va = mlp3(ah, grad, uuv, w);
    float vr = mlp3(ah, grad, uuv, w + 16);
    float v = fmaxf(fabsf(va) - vr, 0.0f);
    return fminf(v, 1.0f);
}

#define LOAD_W(tt) do { if (tid < 32) { int _t = (tt); float v; \
    if      (tid <  9) v = aW1[_t*9 + tid]; \
    else if (tid < 12) v = ab1[_t*3 + (tid-9)]; \
    else if (tid < 15) v = aW2[_t*3 + (tid-12)]; \
    else if (tid < 16) v = ab2[_t]; \
    else if (tid < 25) v = rW1[_t*9 + (tid-16)]; \
    else if (tid < 28) v = rb1[_t*3 + (tid-25)]; \
    else if (tid < 31) v = rW2[_t*3 + (tid-28)]; \
    else               v = rb2[_t]; \
    w[tid] = v; } } while (0)

// lambda/ls update for 128 rows (I-rows in lsI, J-rows in lsJ); also zeroes rs accumulators
#define LAMBDA_PHASE(ROWI, ROWJ) do { if (tid < 128) { \
    int row = (tid < 64) ? ((ROWI) + tid) : ((ROWJ) + tid - 64); \
    float rsv = __hip_atomic_load(&rs_cur[b*LL + row], __ATOMIC_RELAXED, __HIP_MEMORY_SCOPE_AGENT); \
    float lg = fmaxf(rsv - 1.0f, 0.0f); \
    if (t == 0) lam = lg; \
    else { int o = t - 1; \
        float h0 = fmaxf(lW1[o*6+0]*lam + lW1[o*6+1]*lg + lb1[o*3+0], 0.0f); \
        float h1 = fmaxf(lW1[o*6+2]*lam + lW1[o*6+3]*lg + lb1[o*3+1], 0.0f); \
        float h2 = fmaxf(lW1[o*6+4]*lam + lW1[o*6+5]*lg + lb1[o*3+2], 0.0f); \
        lam = fmaxf(lW2[o*3+0]*h0 + lW2[o*3+1]*h1 + lW2[o*3+2]*h2 + lb2[o], 0.0f); } \
    float lsv = lam * sigm(2.0f*(rsv - 1.0f)); \
    if (tid < 64) { lsI[tid] = lsv; rsIb[tid] = 0.0f; } \
    else          { lsJ[tid-64] = lsv; rsJb[tid-64] = 0.0f; } } } while (0)

__global__ __launch_bounds__(256, 4) void k_main(
        const float* __restrict__ u, const float* __restrict__ x,
        float* __restrict__ rs, unsigned int* __restrict__ done,
        float* __restrict__ out,
        const float* __restrict__ aW1, const float* __restrict__ ab1,
        const float* __restrict__ aW2, const float* __restrict__ ab2,
        const float* __restrict__ rW1, const float* __restrict__ rb1,
        const float* __restrict__ rW2, const float* __restrict__ rb2,
        const float* __restrict__ lW1, const float* __restrict__ lb1,
        const float* __restrict__ lW2, const float* __restrict__ lb2) {
    // LDS: 16640*2 + 4160 + 1024 + 256*4 + 128 = 39616 B -> guaranteed 4 blocks/CU
    __shared__ unsigned int stA[TILE * 65];   // packed state tile IJ (lo=uu, hi=ahat)
    __shared__ unsigned int stB[TILE * 65];   // packed state tile JI (diag: second tile)
    __shared__ float buf[16 * 65];            // offdiag a_val chunk staging; diag: x of tile B
    __shared__ float xIl[4 * TILE];
    __shared__ float lsI[TILE], lsJ[TILE];
    __shared__ float rsIb[TILE], rsJb[TILE];
    __shared__ float w[32];

    int gid = blockIdx.x, tid = threadIdx.x;
    int c = tid & 63, rg = tid >> 6;
    float lam = 0.0f;

    if (gid < BB * NOFF) {
        // ================= off-diagonal pair =================
        int b = gid / NOFF, po = gid % NOFF;
        int i = 0; while (po >= NTILE - 1 - i) { po -= NTILE - 1 - i; i++; }
        int I = i, J = i + 1 + po;
        int Ib = I * TILE, Jb = J * TILE;

        float xc0 = x[((size_t)b*LL + Jb + c)*4 + 0], xc1 = x[((size_t)b*LL + Jb + c)*4 + 1];
        float xc2 = x[((size_t)b*LL + Jb + c)*4 + 2], xc3 = x[((size_t)b*LL + Jb + c)*4 + 3];
        float bu_c = xc1, bg_c = xc3, s1_c = xc0 + xc3, s2_c = xc2 + xc1;
        { int row = tid >> 2, k2 = tid & 3;
          xIl[k2*TILE + row] = x[((size_t)b*LL + Ib + row)*4 + k2]; }

        // ---- init: u -> packed LDS state ----
        size_t ubIJ = ((size_t)b*LL + Ib)*LL + Jb;
        size_t ubJI = ((size_t)b*LL + Jb)*LL + Ib;
        #pragma unroll
        for (int k = 0; k < 16; k++) {
            int r = rg + 4*k;
            float uv  = u[ubIJ + (size_t)r*LL + c];
            float uuv = sigm(2.0f*(uv - S_CONST))*uv;
            float ah  = sigm(uuv)*sigm(2.0f*(uuv - S_CONST));
            stA[r*65 + c] = pk2(uuv, ah);
            uv  = u[ubJI + (size_t)r*LL + c];
            uuv = sigm(2.0f*(uv - S_CONST))*uv;
            ah  = sigm(uuv)*sigm(2.0f*(uuv - S_CONST));
            stB[r*65 + c] = pk2(uuv, ah);
        }
        if (tid < 64) rsIb[tid] = 0.0f; else if (tid < 128) rsJb[tid-64] = 0.0f;
        __syncthreads();

        // ---- rowsums of a0 ----
        {
            float aval[16]; float rsJacc = 0.0f;
            #pragma unroll
            for (int k = 0; k < 16; k++) {
                int r = rg + 4*k;
                float ah_ij = hi2f(stA[r*65 + c]);
                float ah_ji = hi2f(stB[c*65 + r]);
                float m = xIl[0*TILE+r]*bu_c + xIl[2*TILE+r]*bg_c
                        + xIl[1*TILE+r]*s1_c + xIl[3*TILE+r]*s2_c;
                float a0 = 0.5f*(ah_ij*ah_ij + ah_ji*ah_ji)*m;
                aval[k] = a0; rsJacc += a0;
            }
            atomicAdd(&rsJb[c], rsJacc);
            #pragma unroll
            for (int p = 0; p < 4; p++) {
                #pragma unroll
                for (int kk = 0; kk < 4; kk++) { int jj = rg + 4*kk; buf[jj*65 + c] = aval[4*p + kk]; }
                RAWBAR();
                { int jj = tid & 15, cc0 = tid >> 4;
                  float part = 0.0f;
                  #pragma unroll
                  for (int s = 0; s < 4; s++) part += buf[jj*65 + (cc0 + 16*s)];
                  atomicAdd(&rsIb[16*p + jj], part); }
                RAWBAR();
            }
            if (tid < 64) atomicAdd(&rs[b*LL + Ib + tid], rsIb[tid]);
            else if (tid < 128) atomicAdd(&rs[b*LL + Jb + (tid-64)], rsJb[tid-64]);
            if (tid < 128) {
                asm volatile("s_waitcnt vmcnt(0)" ::: "memory");
                if (tid == 0)
                    __hip_atomic_fetch_add(&done[(0*128 + b*16 + I)*16], 1u, __ATOMIC_RELAXED, __HIP_MEMORY_SCOPE_AGENT);
                if (tid == 64)
                    __hip_atomic_fetch_add(&done[(0*128 + b*16 + J)*16], 1u, __ATOMIC_RELAXED, __HIP_MEMORY_SCOPE_AGENT);
            }
        }

        // ---- time loop; state stays in LDS; no grid barrier (per-tile done flags) ----
        for (int t = 0; t < TT; t++) {
            LOAD_W(t);
            if (tid == 0)  wait_done(&done[((size_t)t*128 + b*16 + I)*16]);
            if (tid == 64) wait_done(&done[((size_t)t*128 + b*16 + J)*16]);
            RAWBAR();
            asm volatile("" ::: "memory");
            const float* rs_cur = rs + (size_t)t*BB*LL;
            LAMBDA_PHASE(Ib, Jb);
            RAWBAR();

            size_t outBase = (((size_t)t*BB + b)*LL)*LL;
            bool last = (t == TT-1);
            float aval[16]; float rsJacc = 0.0f;
            #pragma unroll
            for (int k = 0; k < 16; k++) {
                int r = rg + 4*k;
                unsigned int vA = stA[r*65 + c], vB = stB[c*65 + r];  // thread-private slots
                float uu_ij = lo2f(vA), ah_ij = hi2f(vA);
                float uu_ji = lo2f(vB), ah_ji = hi2f(vB);
                float m = xIl[0*TILE+r]*bu_c + xIl[2*TILE+r]*bg_c
                        + xIl[1*TILE+r]*s1_c + xIl[3*TILE+r]*s2_c;
                float gsum = -0.5f*(uu_ij + uu_ji) + lsI[r] + lsJ[c];
                float an_ij = ahnew_calc(ah_ij, ah_ij*m*gsum, uu_ij, w);
                float an_ji = ahnew_calc(ah_ji, ah_ji*m*gsum, uu_ji, w);
                float a_val = 0.5f*(an_ij*an_ij + an_ji*an_ji)*m;
                ((unsigned short*)stA)[(r*65 + c)*2 + 1] = f2bf(an_ij);
                ((unsigned short*)stB)[(c*65 + r)*2 + 1] = f2bf(an_ji);
                __builtin_nontemporal_store(a_val, &out[outBase + (size_t)(Ib+r)*LL + (Jb+c)]);
                aval[k] = a_val; rsJacc += a_val;
            }
            atomicAdd(&rsJb[c], rsJacc);

            // staged JI writeback (transpose via LDS, 64B-coalesced) + rsI column sums
            #pragma unroll
            for (int p = 0; p < 4; p++) {
                #pragma unroll
                for (int kk = 0; kk < 4; kk++) { int jj = rg + 4*kk; buf[jj*65 + c] = aval[4*p + kk]; }
                RAWBAR();
                { int jj = tid & 15, cc0 = tid >> 4;
                  float part = 0.0f;
                  #pragma unroll
                  for (int s = 0; s < 4; s++) {
                      int cc = cc0 + 16*s;
                      float v = buf[jj*65 + cc];
                      __builtin_nontemporal_store(v, &out[outBase + (size_t)(Jb+cc)*LL + (Ib + 16*p + jj)]);
                      part += v;
                  }
                  if (!last) atomicAdd(&rsIb[16*p + jj], part); }
                RAWBAR();
            }
            if (!last) {
                float* rs_next = rs + (size_t)(t+1)*BB*LL;
                if (tid < 128) {
                    if (tid < 64) atomicAdd(&rs_next[b*LL + Ib + tid], rsIb[tid]);
                    else          atomicAdd(&rs_next[b*LL + Jb + (tid-64)], rsJb[tid-64]);
                    asm volatile("s_waitcnt vmcnt(0)" ::: "memory");
                    if (tid == 0)
                        __hip_atomic_fetch_add(&done[((size_t)(t+1)*128 + b*16 + I)*16], 1u, __ATOMIC_RELAXED, __HIP_MEMORY_SCOPE_AGENT);
                    if (tid == 64)
                        __hip_atomic_fetch_add(&done[((size_t)(t+1)*128 + b*16 + J)*16], 1u, __ATOMIC_RELAXED, __HIP_MEMORY_SCOPE_AGENT);
                }
            }
        }
    } else {
        // ================= merged diagonal block: two diag tiles =================
        int d = gid - BB*NOFF;          // 0..63
        int g0 = 2*d;
        int b = g0 >> 4;
        int TA = g0 & 15, TB = (g0 & 15) + 1;
        int Ab = TA * TILE, Bb = TB * TILE;
        float* xIlB = buf;              // diag never uses the staging buffer

        float t0, t1, t2, t3;
        t0 = x[((size_t)b*LL + Ab + c)*4 + 0]; t1 = x[((size_t)b*LL + Ab + c)*4 + 1];
        t2 = x[((size_t)b*LL + Ab + c)*4 + 2]; t3 = x[((size_t)b*LL + Ab + c)*4 + 3];
        float buA = t1, bgA = t3, s1A = t0 + t3, s2A = t2 + t1;
        t0 = x[((size_t)b*LL + Bb + c)*4 + 0]; t1 = x[((size_t)b*LL + Bb + c)*4 + 1];
        t2 = x[((size_t)b*LL + Bb + c)*4 + 2]; t3 = x[((size_t)b*LL + Bb + c)*4 + 3];
        float buB = t1, bgB = t3, s1B = t0 + t3, s2B = t2 + t1;
        { int row = tid >> 2, k2 = tid & 3;
          xIl [k2*TILE + row] = x[((size_t)b*LL + Ab + row)*4 + k2];
          xIlB[k2*TILE + row] = x[((size_t)b*LL + Bb + row)*4 + k2]; }

        size_t ubA = ((size_t)b*LL + Ab)*LL + Ab;
        size_t ubB = ((size_t)b*LL + Bb)*LL + Bb;
        #pragma unroll
        for (int k = 0; k < 16; k++) {
            int r = rg + 4*k;
            float uv  = u[ubA + (size_t)r*LL + c];
            float uuv = sigm(2.0f*(uv - S_CONST))*uv;
            float ah  = sigm(uuv)*sigm(2.0f*(uuv - S_CONST));
            stA[r*65 + c] = pk2(uuv, ah);
            uv  = u[ubB + (size_t)r*LL + c];
            uuv = sigm(2.0f*(uv - S_CONST))*uv;
            ah  = sigm(uuv)*sigm(2.0f*(uuv - S_CONST));
            stB[r*65 + c] = pk2(uuv, ah);
        }
        if (tid < 64) rsIb[tid] = 0.0f; else if (tid < 128) rsJb[tid-64] = 0.0f;
        __syncthreads();
        {
            float accA = 0.0f, accB = 0.0f;
            #pragma unroll
            for (int k = 0; k < 16; k++) {
                int r = rg + 4*k;
                float aij = hi2f(stA[r*65 + c]), aji = hi2f(stA[c*65 + r]);
                float m = xIl[0*TILE+r]*buA + xIl[2*TILE+r]*bgA
                        + xIl[1*TILE+r]*s1A + xIl[3*TILE+r]*s2A;
                accA += 0.5f*(aij*aij + aji*aji)*m;
                aij = hi2f(stB[r*65 + c]); aji = hi2f(stB[c*65 + r]);
                m = xIlB[0*TILE+r]*buB + xIlB[2*TILE+r]*bgB
                  + xIlB[1*TILE+r]*s1B + xIlB[3*TILE+r]*s2B;
                accB += 0.5f*(aij*aij + aji*aji)*m;
            }
            atomicAdd(&rsIb[c], accA);    // diag tile symmetric: col sum == row sum
            atomicAdd(&rsJb[c], accB);
            RAWBAR();
            if (tid < 64) atomicAdd(&rs[b*LL + Ab + tid], rsIb[tid]);
            else if (tid < 128) atomicAdd(&rs[b*LL + Bb + (tid-64)], rsJb[tid-64]);
            if (tid < 128) {
                asm volatile("s_waitcnt vmcnt(0)" ::: "memory");
                if (tid == 0)
                    __hip_atomic_fetch_add(&done[(0*128 + b*16 + TA)*16], 1u, __ATOMIC_RELAXED, __HIP_MEMORY_SCOPE_AGENT);
                if (tid == 64)
                    __hip_atomic_fetch_add(&done[(0*128 + b*16 + TB)*16], 1u, __ATOMIC_RELAXED, __HIP_MEMORY_SCOPE_AGENT);
            }
        }

        for (int t = 0; t < TT; t++) {
            LOAD_W(t);
            if (tid == 0)  wait_done(&done[((size_t)t*128 + b*16 + TA)*16]);
            if (tid == 64) wait_done(&done[((size_t)t*128 + b*16 + TB)*16]);
            RAWBAR();
            asm volatile("" ::: "memory");
            const float* rs_cur = rs + (size_t)t*BB*LL;
            LAMBDA_PHASE(Ab, Bb);
            RAWBAR();

            size_t outBase = (((size_t)t*BB + b)*LL)*LL;
            bool last = (t == TT-1);

            // ---- tile A ----
            unsigned int vT[16];
            #pragma unroll
            for (int k = 0; k < 16; k++) vT[k] = stA[c*65 + (rg + 4*k)];
            RAWBAR();
            float acc = 0.0f;
            #pragma unroll
            for (int k = 0; k < 16; k++) {
                int r = rg + 4*k;
                unsigned int vO = stA[r*65 + c];
                float uu_ij = lo2f(vO), ah_ij = hi2f(vO);
                float uu_ji = lo2f(vT[k]), ah_ji = hi2f(vT[k]);
                float m = xIl[0*TILE+r]*buA + xIl[2*TILE+r]*bgA
                        + xIl[1*TILE+r]*s1A + xIl[3*TILE+r]*s2A;
                float gsum = -0.5f*(uu_ij + uu_ji) + lsI[r] + lsI[c];
                float an_ij = ahnew_calc(ah_ij, ah_ij*m*gsum, uu_ij, w);
                float an_ji = ahnew_calc(ah_ji, ah_ji*m*gsum, uu_ji, w);
                float a_val = 0.5f*(an_ij*an_ij + an_ji*an_ji)*m;
                ((unsigned short*)stA)[(r*65 + c)*2 + 1] = f2bf(an_ij);   // own slot only
                __builtin_nontemporal_store(a_val, &out[outBase + (size_t)(Ab+r)*LL + (Ab+c)]);
                acc += a_val;
            }
            if (!last) atomicAdd(&rsIb[c], acc);

            // ---- tile B ----
            #pragma unroll
            for (int k = 0; k < 16; k++) vT[k] = stB[c*65 + (rg + 4*k)];
            RAWBAR();
            acc = 0.0f;
            #pragma unroll
            for (int k = 0; k < 16; k++) {
                int r = rg + 4*k;
                unsigned int vO = stB[r*65 + c];
                float uu_ij = lo2f(vO), ah_ij = hi2f(vO);
                float uu_ji = lo2f(vT[k]), ah_ji = hi2f(vT[k]);
                float m = xIlB[0*TILE+r]*buB + xIlB[2*TILE+r]*bgB
                        + xIlB[1*TILE+r]*s1B + xIlB[3*TILE+r]*s2B;
                float gsum = -0.5f*(uu_ij + uu_ji) + lsJ[r] + lsJ[c];
                float an_ij = ahnew_calc(ah_ij, ah_ij*m*gsum, uu_ij, w);
                float an_ji = ahnew_calc(ah_ji, ah_ji*m*gsum, uu_ji, w);
                float a_val = 0.5f*(an_ij*an_ij + an_ji*an_ji)*m;
                ((unsigned short*)stB)[(r*65 + c)*2 + 1] = f2bf(an_ij);
                __builtin_nontemporal_store(a_val, &out[outBase + (size_t)(Bb+r)*LL + (Bb+c)]);
                acc += a_val;
            }
            if (!last) {
                atomicAdd(&rsJb[c], acc);
                RAWBAR();
                float* rs_next = rs + (size_t)(t+1)*BB*LL;
                if (tid < 128) {
                    if (tid < 64) atomicAdd(&rs_next[b*LL + Ab + tid], rsIb[tid]);
                    else          atomicAdd(&rs_next[b*LL + Bb + (tid-64)], rsJb[tid-64]);
                    asm volatile("s_waitcnt vmcnt(0)" ::: "memory");
                    if (tid == 0)
                        __hip_atomic_fetch_add(&done[((size_t)(t+1)*128 + b*16 + TA)*16], 1u, __ATOMIC_RELAXED, __HIP_MEMORY_SCOPE_AGENT);
                    if (tid == 64)
                        __hip_atomic_fetch_add(&done[((size_t)(t+1)*128 + b*16 + TB)*16], 1u, __ATOMIC_RELAXED, __HIP_MEMORY_SCOPE_AGENT);
                }
            }
        }
    }
}

extern "C" void kernel_launch(void* const* d_in, const int* in_sizes, int n_in,
                              void* d_out, int out_size, void* d_ws, size_t ws_size,
                              hipStream_t stream) {
    const float* u   = (const float*)d_in[0];
    const float* x   = (const float*)d_in[1];
    const float* aW1 = (const float*)d_in[3];
    const float* ab1 = (const float*)d_in[4];
    const float* aW2 = (const float*)d_in[5];
    const float* ab2 = (const float*)d_in[6];
    const float* rW1 = (const float*)d_in[7];
    const float* rb1 = (const float*)d_in[8];
    const float* rW2 = (const float*)d_in[9];
    const float* rb2 = (const float*)d_in[10];
    const float* lW1 = (const float*)d_in[11];
    const float* lb1 = (const float*)d_in[12];
    const float* lW2 = (const float*)d_in[13];
    const float* lb2 = (const float*)d_in[14];
    float* out = (float*)d_out;

    float* rs = (float*)d_ws;                                    // TT rowsum buffers
    unsigned int* done = (unsigned int*)(rs + (size_t)TT*BB*LL); // TT*128 padded counters
    size_t zbytes = (size_t)TT*BB*LL*sizeof(float) + (size_t)TT*128*16*sizeof(unsigned int);
    hipMemsetAsync(rs, 0, zbytes, stream);

    hipLaunchKernelGGL(k_main, dim3(NBLK), dim3(256), 0, stream,
                       u, x, rs, done, out,
                       aW1, ab1, aW2, ab2, rW1, rb1, rW2, rb2,
                       lW1, lb1, lW2, lb2);
}